// Round 5
// baseline (116.726 us; speedup 1.0000x reference)
//
#include <hip/hip_runtime.h>
#include <stdint.h>

#define N_NODES 8192
#define N_EDGES 65536
#define N_TRIPLES (N_EDGES + N_NODES)   // 73728
#define D 768
#define D2 1536
#define NREL 38
#define BATCH 8
#define SENTN 512                        // B*S
#define OUT1_OFF ((size_t)N_TRIPLES * D)                     // 56623104
#define OUT2_OFF (OUT1_OFF + (size_t)BATCH * N_TRIPLES)      // 57212928

typedef __attribute__((ext_vector_type(8))) __bf16 bf16x8;
typedef __attribute__((ext_vector_type(4))) float f32x4;
typedef __attribute__((ext_vector_type(4))) unsigned short ushort4v;

static __device__ __forceinline__ unsigned short f2bf(float f) {
  unsigned u = __builtin_bit_cast(unsigned, f);
  u += 0x7FFFu + ((u >> 16) & 1u);
  return (unsigned short)(u >> 16);
}
static __device__ __forceinline__ float bf2f(unsigned short h) {
  return __builtin_bit_cast(float, ((unsigned)h) << 16);
}

// ================= merged prep =================
// blocks [0,6144): x = bf16(cemb[cids])           (one float4 per thread)
// blocks [6144,7296): W13T transpose->bf16
// blocks [7296,7530): relW2 PARTIALS (39 rels x 6 K-chunks of 128)
// blocks [7530,7562): node mask bits
__global__ void k_prep(const int* __restrict__ cids, const float* __restrict__ cemb,
                       unsigned short* __restrict__ xbf,
                       const float* __restrict__ W, unsigned short* __restrict__ wt,
                       const float* __restrict__ relemb, const float* __restrict__ selfemb,
                       float* __restrict__ partials,
                       const int* __restrict__ sent, unsigned int* __restrict__ nmask) {
  __shared__ __align__(16) char smraw[32 * 33 * 4];
  int b = blockIdx.x;
  if (b < 6144) {
    int t4 = b * 256 + threadIdx.x;
    int row = t4 / (D / 4);
    int c4 = t4 % (D / 4);
    int cid = cids[row];
    float4 v = ((const float4*)(cemb + (size_t)cid * D))[c4];
    ushort4v o;
    o.x = f2bf(v.x); o.y = f2bf(v.y); o.z = f2bf(v.z); o.w = f2bf(v.w);
    *(ushort4v*)(xbf + (size_t)t4 * 4) = o;
  } else if (b < 7296) {
    float (*tile)[33] = (float(*)[33])smraw;
    int idx = b - 6144;
    int kb = (idx % 24) * 32;
    int jb = (idx / 24) * 32;
    int tx = threadIdx.x % 32;
    int ty = threadIdx.x / 32;
#pragma unroll
    for (int i = 0; i < 4; ++i) {
      int k = kb + ty + i * 8;
      int j = jb + tx;
      float v = (j < D) ? W[(size_t)k * D + j] : W[(size_t)(2 * D + k) * D + (j - D)];
      tile[ty + i * 8][tx] = v;
    }
    __syncthreads();
#pragma unroll
    for (int i = 0; i < 4; ++i) {
      int j = jb + ty + i * 8;
      int k = kb + tx;
      wt[(size_t)j * D + k] = f2bf(tile[tx][ty + i * 8]);
    }
  } else if (b < 7530) {
    int idx = b - 7296;        // 0..233
    int r = idx / 6;           // 0..38
    int ch = idx % 6;          // K-chunk of 128
    const float* src = (r < NREL) ? (relemb + (size_t)r * D) : selfemb;
    int c = threadIdx.x;
    const float* W2 = W + (size_t)D * D;
    float a0 = 0.f, a1 = 0.f, a2 = 0.f;
    int k0 = ch * 128;
    for (int k = 0; k < 128; ++k) {
      float s = src[k0 + k];
      const float* wr = W2 + (size_t)(k0 + k) * D;
      a0 += s * wr[c];
      a1 += s * wr[c + 256];
      a2 += s * wr[c + 512];
    }
    float* p = partials + (size_t)idx * D;
    p[c] = a0;
    p[c + 256] = a1;
    p[c + 512] = a2;
  } else {
    int* ls = (int*)smraw;
    for (int i = threadIdx.x; i < SENTN; i += 256) ls[i] = sent[i];
    __syncthreads();
    int n = (b - 7530) * 256 + threadIdx.x;
    int cid = cids[n];
    unsigned m = 0;
#pragma unroll 16
    for (int s = 0; s < SENTN; ++s)
      m |= (ls[s] == cid) ? (1u << (s >> 6)) : 0u;
    nmask[n] = m;
  }
}

// ================= GEMM + side work =================
// blocks [0,768): Cb[8192][1536](bf16) = A * BT^T (+bias on cols<768), counted-vmcnt 2-phase
// blocks [768,807): relW2 reduce (sum 6 partial chunks)
// blocks [807,1095): triple_ids + mask outputs (NT stores)
__global__ void k_gemm(const unsigned short* __restrict__ A,
                       const unsigned short* __restrict__ BT,
                       unsigned short* __restrict__ Cb,
                       const float* __restrict__ partials, float* __restrict__ relw2,
                       const float* __restrict__ bias,
                       const int* __restrict__ cids, const int* __restrict__ eidx,
                       const float* __restrict__ eattr, const unsigned* __restrict__ nmask,
                       float* __restrict__ out) {
  __shared__ __align__(16) unsigned short lsAB[2][2][128 * 64];   // [buf][A/B]
  const int bid = blockIdx.x;
  const int tid = threadIdx.x;

  if (bid >= 768) {
    if (bid < 807) {
      // ---- relW2 reduce: relw2[r][c] = sum_ch partials[r*6+ch][c] ----
      int r = bid - 768;
      int c = tid;
      const float* p = partials + (size_t)r * 6 * D;
#pragma unroll
      for (int j = 0; j < 3; ++j) {
        int cc = c + j * 256;
        float s = 0.f;
#pragma unroll
        for (int ch = 0; ch < 6; ++ch) s += p[(size_t)ch * D + cc];
        relw2[(size_t)r * D + cc] = s;
      }
    } else {
      // ---- triple ids + mask ----
      int t = (bid - 807) * 256 + tid;
      int h, tl;
      float rel;
      if (t < N_EDGES) {
        h = eidx[t];
        tl = eidx[N_EDGES + t];
        rel = (float)(int)eattr[2 * t];
      } else {
        h = t - N_EDGES;
        tl = h;
        rel = (float)NREL;
      }
      float* o2 = out + OUT2_OFF + (size_t)t * 3;
      __builtin_nontemporal_store((float)cids[h], o2 + 0);
      __builtin_nontemporal_store(rel, o2 + 1);
      __builtin_nontemporal_store((float)cids[tl], o2 + 2);
      unsigned m = nmask[h] | nmask[tl];
      float* o1 = out + OUT1_OFF;
#pragma unroll
      for (int bb = 0; bb < BATCH; ++bb)
        __builtin_nontemporal_store(((m >> bb) & 1u) ? 1.0f : 0.0f,
                                    o1 + (size_t)bb * N_TRIPLES + t);
    }
    return;
  }

  const int lane = tid & 63;
  const int wid = tid >> 6;
  const int wr = wid >> 1, wc = wid & 1;

  // XCD-aware bijective swizzle: 768 blocks, 96 per XCD.
  const int swz = (bid & 7) * 96 + (bid >> 3);
  const int arow0 = (swz / 12) * 128;
  const int bcol0 = (swz % 12) * 128;

  f32x4 acc[4][4] = {};

  const int rloc = tid >> 3;                       // 0..31: row within 32-row chunk
  const int gchunk = (tid & 7) ^ (rloc & 7);       // swizzled source col-chunk
  const unsigned short* ga = A + (size_t)(arow0 + rloc) * D + gchunk * 8;
  const unsigned short* gb = BT + (size_t)(bcol0 + rloc) * D + gchunk * 8;
  const int lbo = (tid & ~63) * 8;                 // wave-uniform LDS elem offset

  const int lr = lane & 15;
  const int hi = lane >> 4;

#define STAGE(BUF, K0)                                                                 \
  {                                                                                    \
    unsigned short* dA = &lsAB[BUF][0][lbo];                                           \
    unsigned short* dB = &lsAB[BUF][1][lbo];                                           \
    _Pragma("unroll") for (int c = 0; c < 4; ++c) {                                    \
      __builtin_amdgcn_global_load_lds(                                                \
          (const __attribute__((address_space(1))) void*)(ga + (size_t)c * 32 * D + (K0)), \
          (__attribute__((address_space(3))) void*)(dA + c * 2048), 16, 0, 0);         \
      __builtin_amdgcn_global_load_lds(                                                \
          (const __attribute__((address_space(1))) void*)(gb + (size_t)c * 32 * D + (K0)), \
          (__attribute__((address_space(3))) void*)(dB + c * 2048), 16, 0, 0);         \
    }                                                                                  \
  }

#define COMPUTE(BUF)                                                                   \
  {                                                                                    \
    const unsigned short* sA = lsAB[BUF][0];                                           \
    const unsigned short* sB = lsAB[BUF][1];                                           \
    _Pragma("unroll") for (int kk = 0; kk < 2; ++kk) {                                 \
      const int swc = ((kk * 4 + hi) ^ (lr & 7)) * 8;                                  \
      bf16x8 af[4], bfr[4];                                                            \
      _Pragma("unroll") for (int m = 0; m < 4; ++m)                                    \
          af[m] = *(const bf16x8*)(sA + (wr * 64 + m * 16 + lr) * 64 + swc);           \
      _Pragma("unroll") for (int n = 0; n < 4; ++n)                                    \
          bfr[n] = *(const bf16x8*)(sB + (wc * 64 + n * 16 + lr) * 64 + swc);          \
      _Pragma("unroll") for (int m = 0; m < 4; ++m)                                    \
          _Pragma("unroll") for (int n = 0; n < 4; ++n)                                \
              acc[m][n] = __builtin_amdgcn_mfma_f32_16x16x32_bf16(af[m], bfr[n],       \
                                                                  acc[m][n], 0, 0, 0); \
    }                                                                                  \
  }

  // Counted-vmcnt 2-phase: raw barriers, NEVER drain vmcnt to 0 in steady state.
  STAGE(0, 0)
  STAGE(1, 64)
#pragma unroll
  for (int t = 0; t < 12; ++t) {
    if (t < 11) { asm volatile("s_waitcnt vmcnt(8)" ::: "memory"); }
    else        { asm volatile("s_waitcnt vmcnt(0)" ::: "memory"); }
    __builtin_amdgcn_s_barrier();      // tile t ready in all waves
    if (t & 1) COMPUTE(1) else COMPUTE(0)
    asm volatile("" ::: "memory");     // pin LDS reads before the reuse barrier
    __builtin_amdgcn_s_barrier();      // all waves done reading buf[t&1]
    if (t + 2 < 12) { if (t & 1) STAGE(1, (t + 2) * 64) else STAGE(0, (t + 2) * 64) }
  }
#undef STAGE
#undef COMPUTE

  // Epilogue: fold bias into the xw1 half (cols < 768) so k_out's bias term vanishes.
  // bias rides the UNSCALED x-terms (w multiplies only relW2), so this is exact.
  const int crow = hi * 4;
  const int ccol = lr;
  const bool addb = (bcol0 < D);
#pragma unroll
  for (int m = 0; m < 4; ++m) {
    int row = arow0 + wr * 64 + m * 16 + crow;
#pragma unroll
    for (int n = 0; n < 4; ++n) {
      int col = bcol0 + wc * 64 + n * 16 + ccol;
      float bv = addb ? bias[col] : 0.f;
      unsigned short* cp = Cb + (size_t)row * D2 + col;
#pragma unroll
      for (int r = 0; r < 4; ++r)
        cp[(size_t)r * D2] = f2bf(acc[m][n][r] + bv);
    }
  }
}

// ================= encoded output =================
// encoded[t] = xw1b[head] + w*relW2[rel] + xw3[tail]   (bias pre-folded into xw1b)
// 16 triples/block = 4 per wave: 12 gather loads in flight per j-step (MLP).
__global__ void k_out(const int* __restrict__ eidx, const float* __restrict__ eattr,
                      const unsigned short* __restrict__ xwb, const float* __restrict__ relw2,
                      float* __restrict__ out) {
  const int wid = threadIdx.x >> 6;
  const int lane = threadIdx.x & 63;
  const int t0 = blockIdx.x * 16 + wid * 4;

  const ushort4v* r1[4];
  const ushort4v* r3[4];
  const f32x4* rw[4];
  float w[4];
#pragma unroll
  for (int q = 0; q < 4; ++q) {
    int t = t0 + q;
    if (t < N_EDGES) {
      int h = eidx[t];
      int tl = eidx[N_EDGES + t];
      int rel = (int)eattr[2 * t];
      w[q] = eattr[2 * t + 1];
      r1[q] = (const ushort4v*)(xwb + (size_t)h * D2);
      r3[q] = (const ushort4v*)(xwb + (size_t)tl * D2 + D);
      rw[q] = (const f32x4*)(relw2 + (size_t)rel * D);
    } else {
      int i = t - N_EDGES;
      w[q] = 1.f;
      r1[q] = (const ushort4v*)(xwb + (size_t)i * D2);
      r3[q] = (const ushort4v*)(xwb + (size_t)i * D2 + D);
      rw[q] = (const f32x4*)(relw2 + (size_t)NREL * D);
    }
  }

#pragma unroll
  for (int j = 0; j < 3; ++j) {
    const int c4 = j * 64 + lane;
    ushort4v a4[4], x4[4];
    f32x4 c[4];
#pragma unroll
    for (int q = 0; q < 4; ++q) {
      a4[q] = r1[q][c4];
      x4[q] = r3[q][c4];
      c[q] = rw[q][c4];
    }
#pragma unroll
    for (int q = 0; q < 4; ++q) {
      f32x4 res;
      res.x = bf2f(a4[q].x) + w[q] * c[q].x + bf2f(x4[q].x);
      res.y = bf2f(a4[q].y) + w[q] * c[q].y + bf2f(x4[q].y);
      res.z = bf2f(a4[q].z) + w[q] * c[q].z + bf2f(x4[q].z);
      res.w = bf2f(a4[q].w) + w[q] * c[q].w + bf2f(x4[q].w);
      f32x4* o = (f32x4*)(out + (size_t)(t0 + q) * D);
      __builtin_nontemporal_store(res, &o[c4]);
    }
  }
}

extern "C" void kernel_launch(void* const* d_in, const int* in_sizes, int n_in,
                              void* d_out, int out_size, void* d_ws, size_t ws_size,
                              hipStream_t stream) {
  const int* cids = (const int*)d_in[0];
  const int* eidx = (const int*)d_in[1];
  const float* eattr = (const float*)d_in[2];
  const int* sent = (const int*)d_in[3];
  const float* cemb = (const float*)d_in[4];
  const float* relemb = (const float*)d_in[5];
  const float* selfemb = (const float*)d_in[6];
  const float* W = (const float*)d_in[7];
  const float* bias = (const float*)d_in[8];

  char* ws = (char*)d_ws;
  unsigned short* xbf = (unsigned short*)ws;                         // 12,582,912 B
  unsigned short* wt = (unsigned short*)(ws + 12582912);             //  2,359,296 B
  unsigned short* xwb = (unsigned short*)(ws + 12582912 + 2359296);  // 25,165,824 B (bf16)
  float* relw2 = (float*)(ws + 12582912 + 2359296 + 25165824);       //    119,808 B
  unsigned* nmask = (unsigned*)(ws + 12582912 + 2359296 + 25165824 + 119808);  // 32,768 B
  float* partials = (float*)(ws + 12582912 + 2359296 + 25165824 + 119808 + 32768);  // 718,848 B

  float* out = (float*)d_out;

  k_prep<<<dim3(7562), dim3(256), 0, stream>>>(cids, cemb, xbf, W, wt, relemb, selfemb,
                                               partials, sent, nmask);
  k_gemm<<<dim3(1095), dim3(256), 0, stream>>>(xbf, wt, xwb, partials, relw2, bias,
                                               cids, eidx, eattr, nmask, out);
  k_out<<<dim3(N_TRIPLES / 16), dim3(256), 0, stream>>>(eidx, eattr, xwb, relw2, out);
}